// Round 1
// baseline (317.193 us; speedup 1.0000x reference)
//
#include <hip/hip_runtime.h>

// ViT cls-token-only forward, fp32 throughout.
// B=16, C=8, D=511, H=W=16, DIM=2048, SEQ=512, NH=16, HD=128.
// q = (cls+pos0) @ Wq + bq is batch-independent (one 2048-vector).
// scores[b,h,j] = tok[b,j] . r[h],  r[h] = Wk[:,h*128:+128] @ q[h]  (scaled)
// u[b,h] = sum_j p[b,h,j] * tok[b,j];  ao[b,h] = u[b,h] @ Wv slice + bv
// out[b] = ao[b] @ proj_w + proj_b

#define BB   16
#define CC   8
#define DD   511
#define DIM  2048
#define SEQ  512
#define NH   16
#define HD   128
#define W3   6144
#define SCALE 0.08838834764831845f

// workspace layout (float offsets)
#define Q_OFF   0            // 2048       (atomically accumulated -> memset)
#define AO_OFF  2048         // 32768      (atomically accumulated -> memset)
#define R_OFF   34816        // 32768
#define G_OFF   67584        // 16
#define SC_OFF  67600        // 131072  scores, overwritten in place by softmax p
#define U4_OFF  198672       // 4*16*16*2048 = 2097152 partial u buffers
// total = 2,295,824 floats ~= 9.2 MB

// K1: q[n] = sum_d (cls[d]+pos[d]) * Wq[d][n] + bq[n]   grid (8 ntile, 16 dchunk)
__global__ void k1_q(const float* __restrict__ pos, const float* __restrict__ cls,
                     const float* __restrict__ qkv_w, const float* __restrict__ qkv_b,
                     float* __restrict__ ws) {
  int n  = blockIdx.x * 256 + threadIdx.x;
  int d0 = blockIdx.y * 128;
  float acc = (blockIdx.y == 0) ? qkv_b[n] : 0.f;
  for (int d = d0; d < d0 + 128; ++d) {
    float t0 = cls[d] + pos[d];           // uniform -> scalar load
    acc += t0 * qkv_w[(size_t)d * W3 + n];
  }
  atomicAdd(&ws[Q_OFF + n], acc);
}

// K2: r[h][d] = SCALE * sum_e Wk[d][2048+128h+e] * q[128h+e]   grid (8 dtile, 16 h)
__global__ void k2_r(const float* __restrict__ qkv_w, float* __restrict__ ws) {
  __shared__ float qs[HD];
  int h = blockIdx.y;
  int d = blockIdx.x * 256 + threadIdx.x;
  if (threadIdx.x < HD) qs[threadIdx.x] = ws[Q_OFF + h * HD + threadIdx.x];
  __syncthreads();
  const float4* w4 = reinterpret_cast<const float4*>(qkv_w + (size_t)d * W3 + DIM + h * HD);
  float acc = 0.f;
#pragma unroll
  for (int e4 = 0; e4 < 32; ++e4) {
    float4 w = w4[e4];
    acc += qs[e4*4+0]*w.x + qs[e4*4+1]*w.y + qs[e4*4+2]*w.z + qs[e4*4+3]*w.w;
  }
  ws[R_OFF + h * DIM + d] = acc * SCALE;
}

// K2b: gamma[h] = tok0 . r[h]  (j=0 score; k-bias dropped: softmax shift-invariant)
__global__ void k2b_gamma(const float* __restrict__ pos, const float* __restrict__ cls,
                          float* __restrict__ ws) {
  __shared__ float red[256];
  int h = blockIdx.x, t = threadIdx.x;
  float part = 0.f;
  for (int d = t; d < DIM; d += 256)
    part += (cls[d] + pos[d]) * ws[R_OFF + h * DIM + d];
  red[t] = part;
  __syncthreads();
  for (int s = 128; s > 0; s >>= 1) {
    if (t < s) red[t] += red[t + s];
    __syncthreads();
  }
  if (t == 0) ws[G_OFF + h] = red[0];
}

// K3: scores for j>=1.  grid (64 jgroup, 16 b), 256 thr. thread t holds d=c*256+t.
__global__ void k3_scores(const float* __restrict__ x, const float* __restrict__ pos,
                          float* __restrict__ ws) {
  int g = blockIdx.x, b = blockIdx.y, t = threadIdx.x;
  int wave = t >> 6, lane = t & 63;
  int jbase = 1 + g * 8;
  int nj = min(8, SEQ - jbase);           // last group has 7
  float xv[8][8];
  const size_t xb = (size_t)b * CC * DD * 256;
#pragma unroll
  for (int jj = 0; jj < 8; ++jj) {
    if (jj < nj) {
      int jpos = jbase + jj;
#pragma unroll
      for (int c = 0; c < 8; ++c)
        xv[jj][c] = x[xb + (size_t)c * DD * 256 + (size_t)(jpos - 1) * 256 + t]
                  + pos[jpos * DIM + c * 256 + t];
    } else {
#pragma unroll
      for (int c = 0; c < 8; ++c) xv[jj][c] = 0.f;
    }
  }
  __shared__ float red[NH][8][4];
  for (int h = 0; h < NH; ++h) {
    float rv[8];
#pragma unroll
    for (int c = 0; c < 8; ++c) rv[c] = ws[R_OFF + h * DIM + c * 256 + t];
#pragma unroll
    for (int jj = 0; jj < 8; ++jj) {
      float p = 0.f;
#pragma unroll
      for (int c = 0; c < 8; ++c) p += xv[jj][c] * rv[c];
      for (int m = 1; m < 64; m <<= 1) p += __shfl_xor(p, m, 64);
      if (lane == 0) red[h][jj][wave] = p;
    }
  }
  __syncthreads();
  if (t < NH * 8) {
    int h = t >> 3, jj = t & 7;
    if (jj < nj) {
      float s = red[h][jj][0] + red[h][jj][1] + red[h][jj][2] + red[h][jj][3];
      ws[SC_OFF + (size_t)(b * NH + h) * SEQ + jbase + jj] = s;
    }
  }
}

// K4: softmax per (b,h) row of 512, in place. j=0 score comes from gamma[h].
__global__ void k4_softmax(float* __restrict__ ws) {
  int h = blockIdx.x, b = blockIdx.y, t = threadIdx.x;
  float* sc = ws + SC_OFF + (size_t)(b * NH + h) * SEQ;
  __shared__ float red[256];
  float s0 = (t == 0) ? ws[G_OFF + h] : sc[t];
  float s1 = sc[t + 256];
  red[t] = fmaxf(s0, s1);
  __syncthreads();
  for (int s = 128; s > 0; s >>= 1) { if (t < s) red[t] = fmaxf(red[t], red[t + s]); __syncthreads(); }
  float m = red[0];
  __syncthreads();
  float e0 = __expf(s0 - m), e1 = __expf(s1 - m);
  red[t] = e0 + e1;
  __syncthreads();
  for (int s = 128; s > 0; s >>= 1) { if (t < s) red[t] += red[t + s]; __syncthreads(); }
  float inv = 1.f / red[0];
  sc[t] = e0 * inv;
  sc[t + 256] = e1 * inv;
}

// K5: u4[qc][b][h][d] = sum over j-chunk of p[b,h,j]*tok[b,j][d]. grid (8 c, 4 qc, 16 b).
__global__ void k5_u(const float* __restrict__ x, const float* __restrict__ pos,
                     const float* __restrict__ cls, float* __restrict__ ws) {
  int c = blockIdx.x, qc = blockIdx.y, b = blockIdx.z, t = threadIdx.x;
  int d = c * 256 + t;
  const float* pp = ws + SC_OFF + (size_t)b * NH * SEQ;   // p[h*SEQ + j], uniform loads
  float acc[NH];
  if (qc == 0) {
    float t0 = cls[d] + pos[d];
#pragma unroll
    for (int h = 0; h < NH; ++h) acc[h] = pp[h * SEQ] * t0;   // j=0 cls token
  } else {
#pragma unroll
    for (int h = 0; h < NH; ++h) acc[h] = 0.f;
  }
  int j0 = 1 + qc * 128;
  int nj = min(128, SEQ - j0);            // qc==3 -> 127
  const size_t xb = (size_t)b * CC * DD * 256 + (size_t)c * DD * 256 + t;
  for (int jt = 0; jt < nj; jt += 16) {
    int jn = min(16, nj - jt);
    float xvv[16];
    for (int jj = 0; jj < jn; ++jj) {
      int jpos = j0 + jt + jj;
      xvv[jj] = x[xb + (size_t)(jpos - 1) * 256] + pos[jpos * DIM + c * 256 + t];
    }
    if (jn == 16) {
#pragma unroll
      for (int h = 0; h < NH; ++h) {
        const float* ph = pp + h * SEQ + j0 + jt;
        float a = acc[h];
#pragma unroll
        for (int jj = 0; jj < 16; ++jj) a += ph[jj] * xvv[jj];
        acc[h] = a;
      }
    } else {
      for (int h = 0; h < NH; ++h) {
        const float* ph = pp + h * SEQ + j0 + jt;
        float a = acc[h];
        for (int jj = 0; jj < jn; ++jj) a += ph[jj] * xvv[jj];
        acc[h] = a;
      }
    }
  }
  float* u = ws + U4_OFF + (size_t)((qc * BB + b) * NH) * DIM + d;
#pragma unroll
  for (int h = 0; h < NH; ++h) u[(size_t)h * DIM] = acc[h];
}

// K6: ao[b][m] = sum_d u[b][h][d]*Wv[d][4096+m] + bv[m], m=h*128+e. grid (8 nt, 8 dc, 16 b)
__global__ void k6_ao(const float* __restrict__ qkv_w, const float* __restrict__ qkv_b,
                      float* __restrict__ ws) {
  int nt = blockIdx.x, dc = blockIdx.y, b = blockIdx.z, t = threadIdx.x;
  int m = nt * 256 + t;
  int h0 = nt * 2;                        // 2 heads per 256-wide n tile
  __shared__ float us[2][256];
  int d0 = dc * 256;
  for (int i = t; i < 512; i += 256) {
    int hh = i >> 8, dd = i & 255;
    float s = 0.f;
#pragma unroll
    for (int q = 0; q < 4; ++q)
      s += ws[U4_OFF + (size_t)((q * BB + b) * NH + (h0 + hh)) * DIM + d0 + dd];
    us[hh][dd] = s;
  }
  __syncthreads();
  int hl = t >> 7;
  float acc = (dc == 0) ? qkv_b[2 * DIM + m] : 0.f;
  const float* wcol = qkv_w + (size_t)d0 * W3 + 2 * DIM + m;
  for (int dd = 0; dd < 256; ++dd)
    acc += us[hl][dd] * wcol[(size_t)dd * W3];
  atomicAdd(&ws[AO_OFF + b * DIM + m], acc);
}

// K7: out[b][n] = sum_m ao[b][m]*proj_w[m][n] + proj_b[n]. grid (8 nt, 8 mc, 16 b)
__global__ void k7_out(const float* __restrict__ proj_w, const float* __restrict__ proj_b,
                       const float* __restrict__ ws, float* __restrict__ out) {
  int nt = blockIdx.x, mc = blockIdx.y, b = blockIdx.z, t = threadIdx.x;
  int n = nt * 256 + t;
  __shared__ float as[256];
  as[t] = ws[AO_OFF + b * DIM + mc * 256 + t];
  __syncthreads();
  float acc = (mc == 0) ? proj_b[n] : 0.f;
  const float* wcol = proj_w + (size_t)(mc * 256) * DIM + n;
  for (int mm = 0; mm < 256; ++mm)
    acc += as[mm] * wcol[(size_t)mm * DIM];
  atomicAdd(&out[b * DIM + n], acc);
}

extern "C" void kernel_launch(void* const* d_in, const int* in_sizes, int n_in,
                              void* d_out, int out_size, void* d_ws, size_t ws_size,
                              hipStream_t stream) {
  const float* x      = (const float*)d_in[0];
  const float* pos    = (const float*)d_in[1];
  const float* cls    = (const float*)d_in[2];
  const float* qkv_w  = (const float*)d_in[3];
  const float* qkv_b  = (const float*)d_in[4];
  const float* proj_w = (const float*)d_in[5];
  const float* proj_b = (const float*)d_in[6];
  float* ws  = (float*)d_ws;
  float* out = (float*)d_out;

  // zero the atomically-accumulated regions (q + ao are contiguous) and d_out
  hipMemsetAsync(ws, 0, (size_t)(2048 + 32768) * sizeof(float), stream);
  hipMemsetAsync(out, 0, (size_t)out_size * sizeof(float), stream);

  k1_q      <<<dim3(8, 16),    256, 0, stream>>>(pos, cls, qkv_w, qkv_b, ws);
  k2_r      <<<dim3(8, 16),    256, 0, stream>>>(qkv_w, ws);
  k2b_gamma <<<16,             256, 0, stream>>>(pos, cls, ws);
  k3_scores <<<dim3(64, 16),   256, 0, stream>>>(x, pos, ws);
  k4_softmax<<<dim3(16, 16),   256, 0, stream>>>(ws);
  k5_u      <<<dim3(8, 4, 16), 256, 0, stream>>>(x, pos, cls, ws);
  k6_ao     <<<dim3(8, 8, 16), 256, 0, stream>>>(qkv_w, qkv_b, ws);
  k7_out    <<<dim3(8, 8, 16), 256, 0, stream>>>(proj_w, proj_b, ws, out);
}

// Round 2
// 287.085 us; speedup vs baseline: 1.1049x; 1.1049x over previous
//
#include <hip/hip_runtime.h>

// ViT cls-token-only forward, fp32 throughout.
// B=16, C=8, D=511, H=W=16, DIM=2048, SEQ=512, NH=16, HD=128.
// q = (cls+pos0) @ Wq + bq is batch-independent (one 2048-vector).
// scores[b,h,j] = tok[b,j] . r[h],  r[h] = Wk[:,h*128:+128] @ q[h]  (scaled)
// u[b,h] = sum_j p[b,h,j] * tok[b,j];  ao[b,h] = u[b,h] @ Wv slice + bv
// out[b] = ao[b] @ proj_w + proj_b
//
// R2: parallelism pass. Every reduction dimension split across more blocks:
// k1 128->512 blocks, k2 128->256, k5 512->1024 (8 u-partials), k6/k7
// 1024->2048 (serial loops 256->128). k3 kept: its shuffle-reduce cost is
// per-output, so more blocks would duplicate work.

#define BB   16
#define CC   8
#define DD   511
#define DIM  2048
#define SEQ  512
#define NH   16
#define HD   128
#define W3   6144
#define SCALE 0.08838834764831845f

// workspace layout (float offsets)
#define Q_OFF   0            // 2048   (atomic -> memset)
#define AO_OFF  2048         // 32768  (atomic -> memset)
#define R_OFF   34816        // 32768  (atomic -> memset)
#define G_OFF   67584        // 16
#define SC_OFF  67600        // 131072 scores, overwritten in place by softmax
#define U8_OFF  198672       // 8*16*16*2048 = 4194304 partial u buffers
// total = 4,392,976 floats ~= 17.6 MB

// K1: q[n] = sum_d (cls[d]+pos[d]) * Wq[d][n] + bq[n]   grid (8 ntile, 64 dchunk)
__global__ __launch_bounds__(256) void k1_q(
    const float* __restrict__ pos, const float* __restrict__ cls,
    const float* __restrict__ qkv_w, const float* __restrict__ qkv_b,
    float* __restrict__ ws) {
  int n  = blockIdx.x * 256 + threadIdx.x;
  int d0 = blockIdx.y * 32;
  float acc = (blockIdx.y == 0) ? qkv_b[n] : 0.f;
#pragma unroll 8
  for (int d = d0; d < d0 + 32; ++d) {
    float t0 = cls[d] + pos[d];           // uniform -> scalar load
    acc += t0 * qkv_w[(size_t)d * W3 + n];
  }
  atomicAdd(&ws[Q_OFF + n], acc);
}

// K2: r[h][d] += SCALE * sum over half e-range of Wk[d][2048+128h+e]*q[128h+e]
// grid (8 dtile, 16 h, 2 ehalf)
__global__ __launch_bounds__(256) void k2_r(
    const float* __restrict__ qkv_w, float* __restrict__ ws) {
  __shared__ float qs[64];
  int h = blockIdx.y, ec = blockIdx.z;
  int d = blockIdx.x * 256 + threadIdx.x;
  if (threadIdx.x < 64) qs[threadIdx.x] = ws[Q_OFF + h * HD + ec * 64 + threadIdx.x];
  __syncthreads();
  const float4* w4 = reinterpret_cast<const float4*>(
      qkv_w + (size_t)d * W3 + DIM + h * HD + ec * 64);
  float acc = 0.f;
#pragma unroll
  for (int e4 = 0; e4 < 16; ++e4) {
    float4 w = w4[e4];
    acc += qs[e4*4+0]*w.x + qs[e4*4+1]*w.y + qs[e4*4+2]*w.z + qs[e4*4+3]*w.w;
  }
  atomicAdd(&ws[R_OFF + h * DIM + d], acc * SCALE);
}

// K2b: gamma[h] = tok0 . r[h]  (j=0 score; k-bias dropped: softmax shift-invariant)
__global__ __launch_bounds__(256) void k2b_gamma(
    const float* __restrict__ pos, const float* __restrict__ cls,
    float* __restrict__ ws) {
  __shared__ float red[256];
  int h = blockIdx.x, t = threadIdx.x;
  float part = 0.f;
  for (int d = t; d < DIM; d += 256)
    part += (cls[d] + pos[d]) * ws[R_OFF + h * DIM + d];
  red[t] = part;
  __syncthreads();
  for (int s = 128; s > 0; s >>= 1) {
    if (t < s) red[t] += red[t + s];
    __syncthreads();
  }
  if (t == 0) ws[G_OFF + h] = red[0];
}

// K3: scores for j>=1.  grid (64 jgroup, 16 b), 256 thr. thread t holds d=c*256+t.
__global__ __launch_bounds__(256) void k3_scores(
    const float* __restrict__ x, const float* __restrict__ pos,
    float* __restrict__ ws) {
  int g = blockIdx.x, b = blockIdx.y, t = threadIdx.x;
  int wave = t >> 6, lane = t & 63;
  int jbase = 1 + g * 8;
  int nj = min(8, SEQ - jbase);           // last group has 7
  float xv[8][8];
  const size_t xb = (size_t)b * CC * DD * 256;
#pragma unroll
  for (int jj = 0; jj < 8; ++jj) {
    if (jj < nj) {
      int jpos = jbase + jj;
#pragma unroll
      for (int c = 0; c < 8; ++c)
        xv[jj][c] = x[xb + (size_t)c * DD * 256 + (size_t)(jpos - 1) * 256 + t]
                  + pos[jpos * DIM + c * 256 + t];
    } else {
#pragma unroll
      for (int c = 0; c < 8; ++c) xv[jj][c] = 0.f;
    }
  }
  __shared__ float red[NH][8][4];
  for (int h = 0; h < NH; ++h) {
    float rv[8];
#pragma unroll
    for (int c = 0; c < 8; ++c) rv[c] = ws[R_OFF + h * DIM + c * 256 + t];
#pragma unroll
    for (int jj = 0; jj < 8; ++jj) {
      float p = 0.f;
#pragma unroll
      for (int c = 0; c < 8; ++c) p += xv[jj][c] * rv[c];
      for (int m = 1; m < 64; m <<= 1) p += __shfl_xor(p, m, 64);
      if (lane == 0) red[h][jj][wave] = p;
    }
  }
  __syncthreads();
  if (t < NH * 8) {
    int h = t >> 3, jj = t & 7;
    if (jj < nj) {
      float s = red[h][jj][0] + red[h][jj][1] + red[h][jj][2] + red[h][jj][3];
      ws[SC_OFF + (size_t)(b * NH + h) * SEQ + jbase + jj] = s;
    }
  }
}

// K4: softmax per (b,h) row of 512, in place. j=0 score comes from gamma[h].
__global__ __launch_bounds__(256) void k4_softmax(float* __restrict__ ws) {
  int h = blockIdx.x, b = blockIdx.y, t = threadIdx.x;
  float* sc = ws + SC_OFF + (size_t)(b * NH + h) * SEQ;
  __shared__ float red[256];
  float s0 = (t == 0) ? ws[G_OFF + h] : sc[t];
  float s1 = sc[t + 256];
  red[t] = fmaxf(s0, s1);
  __syncthreads();
  for (int s = 128; s > 0; s >>= 1) { if (t < s) red[t] = fmaxf(red[t], red[t + s]); __syncthreads(); }
  float m = red[0];
  __syncthreads();
  float e0 = __expf(s0 - m), e1 = __expf(s1 - m);
  red[t] = e0 + e1;
  __syncthreads();
  for (int s = 128; s > 0; s >>= 1) { if (t < s) red[t] += red[t + s]; __syncthreads(); }
  float inv = 1.f / red[0];
  sc[t] = e0 * inv;
  sc[t + 256] = e1 * inv;
}

// K5: u8[qc][b][h][d] = sum over 64-j chunk of p[b,h,j]*tok[b,j][d].
// grid (8 c, 8 qc, 16 b).
__global__ __launch_bounds__(256) void k5_u(
    const float* __restrict__ x, const float* __restrict__ pos,
    const float* __restrict__ cls, float* __restrict__ ws) {
  int c = blockIdx.x, qc = blockIdx.y, b = blockIdx.z, t = threadIdx.x;
  int d = c * 256 + t;
  const float* pp = ws + SC_OFF + (size_t)b * NH * SEQ;   // p[h*SEQ+j], uniform
  float acc[NH];
  if (qc == 0) {
    float t0 = cls[d] + pos[d];
#pragma unroll
    for (int h = 0; h < NH; ++h) acc[h] = pp[h * SEQ] * t0;   // j=0 cls token
  } else {
#pragma unroll
    for (int h = 0; h < NH; ++h) acc[h] = 0.f;
  }
  int j0 = 1 + qc * 64;
  int nj = min(64, SEQ - j0);             // qc==7 -> 63
  const size_t xb = (size_t)b * CC * DD * 256 + (size_t)c * DD * 256 + t;
  for (int jt = 0; jt < nj; jt += 16) {
    int jn = min(16, nj - jt);
    float xvv[16];
    for (int jj = 0; jj < jn; ++jj) {
      int jpos = j0 + jt + jj;
      xvv[jj] = x[xb + (size_t)(jpos - 1) * 256] + pos[jpos * DIM + c * 256 + t];
    }
    if (jn == 16) {
#pragma unroll
      for (int h = 0; h < NH; ++h) {
        const float* ph = pp + h * SEQ + j0 + jt;
        float a = acc[h];
#pragma unroll
        for (int jj = 0; jj < 16; ++jj) a += ph[jj] * xvv[jj];
        acc[h] = a;
      }
    } else {
      for (int h = 0; h < NH; ++h) {
        const float* ph = pp + h * SEQ + j0 + jt;
        float a = acc[h];
        for (int jj = 0; jj < jn; ++jj) a += ph[jj] * xvv[jj];
        acc[h] = a;
      }
    }
  }
  float* u = ws + U8_OFF + (size_t)((qc * BB + b) * NH) * DIM + d;
#pragma unroll
  for (int h = 0; h < NH; ++h) u[(size_t)h * DIM] = acc[h];
}

// K6: ao[b][m] += sum over 128-d chunk of u[b][h][d]*Wv[d][4096+m] (+bv),
// m = h*128+e. grid (8 nt, 16 dc, 16 b)
__global__ __launch_bounds__(256) void k6_ao(
    const float* __restrict__ qkv_w, const float* __restrict__ qkv_b,
    float* __restrict__ ws) {
  int nt = blockIdx.x, dc = blockIdx.y, b = blockIdx.z, t = threadIdx.x;
  int m = nt * 256 + t;
  int h0 = nt * 2;                        // 2 heads per 256-wide n tile
  __shared__ float us[2][128];
  int d0 = dc * 128;
  {
    int hh = t >> 7, dd = t & 127;        // one LDS entry per thread
    float s = 0.f;
#pragma unroll
    for (int q = 0; q < 8; ++q)
      s += ws[U8_OFF + (size_t)((q * BB + b) * NH + (h0 + hh)) * DIM + d0 + dd];
    us[hh][dd] = s;
  }
  __syncthreads();
  int hl = t >> 7;
  float acc = (dc == 0) ? qkv_b[2 * DIM + m] : 0.f;
  const float* wcol = qkv_w + (size_t)d0 * W3 + 2 * DIM + m;
#pragma unroll 8
  for (int dd = 0; dd < 128; ++dd)
    acc += us[hl][dd] * wcol[(size_t)dd * W3];
  atomicAdd(&ws[AO_OFF + b * DIM + m], acc);
}

// K7: out[b][n] += sum over 128-m chunk of ao[b][m]*proj_w[m][n] (+pb).
// grid (8 nt, 16 mc, 16 b)
__global__ __launch_bounds__(256) void k7_out(
    const float* __restrict__ proj_w, const float* __restrict__ proj_b,
    const float* __restrict__ ws, float* __restrict__ out) {
  int nt = blockIdx.x, mc = blockIdx.y, b = blockIdx.z, t = threadIdx.x;
  int n = nt * 256 + t;
  __shared__ float as[128];
  if (t < 128) as[t] = ws[AO_OFF + b * DIM + mc * 128 + t];
  __syncthreads();
  float acc = (mc == 0) ? proj_b[n] : 0.f;
  const float* wcol = proj_w + (size_t)(mc * 128) * DIM + n;
#pragma unroll 8
  for (int mm = 0; mm < 128; ++mm)
    acc += as[mm] * wcol[(size_t)mm * DIM];
  atomicAdd(&out[b * DIM + n], acc);
}

extern "C" void kernel_launch(void* const* d_in, const int* in_sizes, int n_in,
                              void* d_out, int out_size, void* d_ws, size_t ws_size,
                              hipStream_t stream) {
  const float* x      = (const float*)d_in[0];
  const float* pos    = (const float*)d_in[1];
  const float* cls    = (const float*)d_in[2];
  const float* qkv_w  = (const float*)d_in[3];
  const float* qkv_b  = (const float*)d_in[4];
  const float* proj_w = (const float*)d_in[5];
  const float* proj_b = (const float*)d_in[6];
  float* ws  = (float*)d_ws;
  float* out = (float*)d_out;

  // zero the atomically-accumulated regions (q, ao, r contiguous) and d_out
  hipMemsetAsync(ws, 0, (size_t)(2048 + 32768 + 32768) * sizeof(float), stream);
  hipMemsetAsync(out, 0, (size_t)out_size * sizeof(float), stream);

  k1_q      <<<dim3(8, 64),     256, 0, stream>>>(pos, cls, qkv_w, qkv_b, ws);
  k2_r      <<<dim3(8, 16, 2),  256, 0, stream>>>(qkv_w, ws);
  k2b_gamma <<<16,              256, 0, stream>>>(pos, cls, ws);
  k3_scores <<<dim3(64, 16),    256, 0, stream>>>(x, pos, ws);
  k4_softmax<<<dim3(16, 16),    256, 0, stream>>>(ws);
  k5_u      <<<dim3(8, 8, 16),  256, 0, stream>>>(x, pos, cls, ws);
  k6_ao     <<<dim3(8, 16, 16), 256, 0, stream>>>(qkv_w, qkv_b, ws);
  k7_out    <<<dim3(8, 16, 16), 256, 0, stream>>>(proj_w, proj_b, ws, out);
}